// Round 5
// baseline (1536.197 us; speedup 1.0000x reference)
//
#include <hip/hip_runtime.h>

// GoL CNN v6 = v5 bugfixed: per layer GEMM M=32(co) x N=16384 x K=32768,
// 16 K-slices (2ch). Block = (batch b, slice s): A-slice 128KB via 4 dbuf LDS
// phases; B rows staged once (f32->relu->f16, mwrap gather). Waves own 4 oy,
// full slice-K -> no cross-wave reduce; partials via f32 atomicAdd.
// Fixes vs v5: (1) WfH layer stride 1048576 f16 (was 524288 — fatal),
// (2) Bsh row stride 104 f16 so f16x8 LDS stores are 16B-aligned (was 100),
// (3) !PRE prefA chunk decode e>>9/&63 (was e>>10/&127, dormant).

typedef _Float16 f16;
typedef _Float16 f16x8 __attribute__((ext_vector_type(8)));
typedef float f32x4 __attribute__((ext_vector_type(4)));
typedef float f32x16 __attribute__((ext_vector_type(16)));

__device__ __forceinline__ int mwrap(int j) {
  int t = j - 31;
  if ((unsigned)t <= 31u) return t;  // middle
  return (j & 1) ? 0 : 31;           // both borders alternate
}

#define BROW 104  // f16 per Bsh row (208 B, 16B-aligned); 52 dwords

template <int NPH, int KYPP, bool RELUIN, bool PRE, bool INCONV>
__global__ __launch_bounds__(512, 2) void gemm5(
    const f16* __restrict__ Wf,     // frag-major f16 weights (layer base), PRE
    const float* __restrict__ Wraw, // raw fp32 weights (layer base), !PRE
    const float* __restrict__ src,  // f32 activations [16][CIN][32][32]
    const float* __restrict__ bias, // [32]
    float* __restrict__ dst) {      // f32 [16][32][32][32], pre-zeroed
  constexpr int NCH = INCONV ? 1 : (NPH * KYPP / 32);
  constexpr int SLICES = INCONV ? 4 : 16;
  constexpr int ABYTES = KYPP * 2048;
  constexpr int UPT = KYPP / 4;
  constexpr int CINW = INCONV ? 1 : 32;

  __shared__ __align__(16) char smem[2 * ABYTES + NCH * 32 * BROW * 2 + 16];
  f16* Bsh = (f16*)(smem + 2 * ABYTES);

  const int tid = threadIdx.x;
  const int lane = tid & 63;
  const int w = tid >> 6;      // wave 0..7 owns oy 4w..4w+3
  const int ox = lane & 31;
  const int sl = lane >> 5;
  const int oy0 = w * 4;
  const int sli = blockIdx.x & (SLICES - 1);
  const int b = blockIdx.x / SLICES;
  const int c0 = INCONV ? 0 : 2 * sli;
  const int ky0 = INCONV ? 8 * sli : 0;

  const f16* Wsl = Wf + ((size_t)(c0 * 32 + ky0) << 10);

  // --- stage B rows once: Bsh[cl][y][0..95] = relu?(src[b][c0+cl][y][mwrap(x')])
  {
    const int NB = NCH * 384;
    for (int base = 0; base < NB; base += 512) {
      const int id = base + tid;
      if (id < NB) {
        const int cl = id / 384, rem = id % 384;
        const int y = rem / 12, u9 = rem % 12;
        const float* sp = src + (((size_t)b * CINW + c0 + cl) * 32 + y) * 32;
        f16x8 v;
#pragma unroll
        for (int i = 0; i < 8; ++i) {
          float t = sp[mwrap(u9 * 8 + i)];
          if (RELUIN) t = fmaxf(t, 0.f);
          v[i] = (f16)t;
        }
        *(f16x8*)(Bsh + (cl * 32 + y) * BROW + u9 * 8) = v;
      }
    }
  }

  int4 pf[UPT];
  auto prefA = [&](int ph1) {
    if constexpr (PRE) {
      const char* gp = (const char*)Wsl + (size_t)ph1 * ABYTES;
#pragma unroll
      for (int u = 0; u < UPT; ++u)
        pf[u] = *(const int4*)(gp + (u * 512 + tid) * 16);
    } else {
#pragma unroll
      for (int u = 0; u < UPT; ++u) {
        const int e = (u * 512 + tid) * 8;
        const int chk = e >> 9, li = (e >> 3) & 63;
        const int co = li & 31, ss = li >> 5;
        const int kk = chk >> 1, kxh = chk & 1;
        const int g = ph1 * KYPP + kk;
        const int cl = g >> 5, kyg = ky0 + (g & 31);
        const float* sp = Wraw + (((size_t)co * CINW + c0 + cl) * 32 + kyg) * 32 +
                          kxh * 16 + ss * 8;
        f32x4 a0 = *(const f32x4*)sp;
        f32x4 a1 = *(const f32x4*)(sp + 4);
        f16x8 v;
        v[0] = (f16)a0[0]; v[1] = (f16)a0[1]; v[2] = (f16)a0[2]; v[3] = (f16)a0[3];
        v[4] = (f16)a1[0]; v[5] = (f16)a1[1]; v[6] = (f16)a1[2]; v[7] = (f16)a1[3];
        pf[u] = __builtin_bit_cast(int4, v);
      }
    }
  };
  auto wrA = [&](int nb) {
    char* lp = smem + nb * ABYTES;
#pragma unroll
    for (int u = 0; u < UPT; ++u)
      *(int4*)(lp + (u * 512 + tid) * 16) = pf[u];
  };

  prefA(0);
  wrA(0);
  __syncthreads();

  f32x16 acc[4] = {};
  f16x8 Bw[2][4][2];  // [parity][t(oy)][kxh] rolling window
  const int Rbase = ox + 4 * sl;

  auto loadB = [&](int cloc, int j, int kxh) -> f16x8 {
    const int y = mwrap(j);
    const int* R = (const int*)Bsh + (cloc * 32 + y) * (BROW / 2) + Rbase + 8 * kxh;
    int4 t;
    t.x = R[0]; t.y = R[1]; t.z = R[2]; t.w = R[3];
    return __builtin_bit_cast(f16x8, t);
  };

  for (int ph = 0; ph < NPH; ++ph) {
    if (ph + 1 < NPH) prefA(ph + 1);
    const char* Ab = smem + (ph & 1) * ABYTES;
#pragma unroll
    for (int kk = 0; kk < KYPP; ++kk) {
      const int g = ph * KYPP + kk;
      const int cloc = g >> 5;
      const int ky = ky0 + (g & 31);
      const int p = g & 1;
      const int J0 = 2 * oy0 + ky;
      if ((g & 31) < 2) {
#pragma unroll
        for (int t = 0; t < 4; ++t) {
          Bw[p][t][0] = loadB(cloc, J0 + 2 * t, 0);
          Bw[p][t][1] = loadB(cloc, J0 + 2 * t, 1);
        }
      } else {
#pragma unroll
        for (int t = 0; t < 3; ++t) {
          Bw[p][t][0] = Bw[p][t + 1][0];
          Bw[p][t][1] = Bw[p][t + 1][1];
        }
        Bw[p][3][0] = loadB(cloc, J0 + 6, 0);
        Bw[p][3][1] = loadB(cloc, J0 + 6, 1);
      }
#pragma unroll
      for (int kxh = 0; kxh < 2; ++kxh) {
        f16x8 a = *(const f16x8*)(Ab + (kk * 2 + kxh) * 1024 + lane * 16);
#pragma unroll
        for (int t = 0; t < 4; ++t)
          acc[t] = __builtin_amdgcn_mfma_f32_32x32x16_f16(a, Bw[p][t][kxh], acc[t], 0, 0, 0);
      }
    }
    if (ph + 1 < NPH) wrA((ph + 1) & 1);
    __syncthreads();
  }

  // epilogue: partial K-sum -> atomic f32; slice 0 adds bias once
  const bool sliceZero = (sli == 0);
#pragma unroll
  for (int t = 0; t < 4; ++t) {
    const int oy = oy0 + t;
#pragma unroll
    for (int r = 0; r < 16; ++r) {
      const int co = (r & 3) + 8 * (r >> 2) + 4 * sl;  // m74/m101 C-layout
      float v = acc[t][r];
      if (sliceZero) v += bias[co];
      atomicAdd(dst + (((size_t)b * 32 + co) * 32 + oy) * 32 + ox, v);
    }
  }
}

// frag-major f16 weights (layout validated in v3/v4)
__global__ void convert_w3(const float* __restrict__ in_w,
                           const float* __restrict__ convs_w,
                           f16* __restrict__ WfIn, f16* __restrict__ WfH) {
  const int total = 4096 + 20 * 131072;
  for (int g = blockIdx.x * blockDim.x + threadIdx.x; g < total;
       g += gridDim.x * blockDim.x) {
    const float* src;
    f16* dst;
    int chunk, lanE, c, ky, kxh;
    if (g < 4096) {
      chunk = g >> 6; lanE = g & 63;
      kxh = chunk & 1; ky = chunk >> 1; c = 0;
      const int co = lanE & 31, ss = lanE >> 5;
      src = in_w + ((size_t)co * 32 + ky) * 32 + kxh * 16 + ss * 8;
      dst = WfIn + (size_t)chunk * 512 + lanE * 8;
    } else {
      const int h = g - 4096;
      const int layer = h >> 17, r = h & 131071;
      chunk = r >> 6; lanE = r & 63;
      kxh = chunk & 1;
      const int t = chunk >> 1;
      ky = t & 31; c = t >> 5;
      const int co = lanE & 31, ss = lanE >> 5;
      src = convs_w + (size_t)layer * 1048576 +
            ((size_t)(co * 32 + c) * 32 + ky) * 32 + kxh * 16 + ss * 8;
      dst = WfH + (size_t)layer * 1048576 + (size_t)chunk * 512 + lanE * 8;
    }
    f32x4 u0 = *(const f32x4*)src;
    f32x4 u1 = *(const f32x4*)(src + 4);
    f16x8 v;
    v[0] = (f16)u0[0]; v[1] = (f16)u0[1]; v[2] = (f16)u0[2]; v[3] = (f16)u0[3];
    v[4] = (f16)u1[0]; v[5] = (f16)u1[1]; v[6] = (f16)u1[2]; v[7] = (f16)u1[3];
    *(f16x8*)dst = v;
  }
}

// 1x1 out conv, reads final f32 buffer with relu
__global__ void out_conv5(const float* __restrict__ hb,
                          const float* __restrict__ ow,
                          const float* __restrict__ ob,
                          float* __restrict__ out) {
  const int o = blockIdx.x * 256 + threadIdx.x;  // 16384
  const int b = o >> 10, rem = o & 1023;
  float s = ob[0];
#pragma unroll
  for (int c = 0; c < 32; ++c)
    s += ow[c] * fmaxf(hb[((size_t)b * 32 + c) * 1024 + rem], 0.f);
  out[o] = s;
}

extern "C" void kernel_launch(void* const* d_in, const int* in_sizes, int n_in,
                              void* d_out, int out_size, void* d_ws,
                              size_t ws_size, hipStream_t stream) {
  const float* x = (const float*)d_in[0];
  const float* in_w = (const float*)d_in[1];
  const float* in_b = (const float*)d_in[2];
  const float* convs_w = (const float*)d_in[3];
  const float* convs_b = (const float*)d_in[4];
  const float* out_w = (const float*)d_in[5];
  const float* out_b = (const float*)d_in[6];
  float* out = (float*)d_out;

  char* ws = (char*)d_ws;
  const size_t BUF = 2097152;
  float* bufA = (float*)ws;
  float* bufB = (float*)(ws + BUF);
  f16* WfIn = (f16*)(ws + 2 * BUF);           // 64 KB
  f16* WfH = (f16*)(ws + 2 * BUF + 65536);    // 40 MB (20 layers x 1048576 f16)
  const bool pre = (ws_size >= 2 * BUF + 65536 + 41943040ull);

  hipMemsetAsync(bufA, 0, BUF, stream);
  hipMemsetAsync(bufB, 0, BUF, stream);
  if (pre) convert_w3<<<2048, 256, 0, stream>>>(in_w, convs_w, WfIn, WfH);

  // in_conv: 4 ky-slices, grid 64
  if (pre)
    gemm5<1, 8, false, true, true><<<64, 512, 0, stream>>>(WfIn, in_w, x, in_b, bufA);
  else
    gemm5<1, 8, false, false, true><<<64, 512, 0, stream>>>(WfIn, in_w, x, in_b, bufA);

  for (int l = 0; l < 20; ++l) {
    const float* cur = (l & 1) ? bufB : bufA;
    float* nxt = (l & 1) ? bufA : bufB;
    if (l >= 1) hipMemsetAsync(nxt, 0, BUF, stream);
    const f16* Wl = WfH + (size_t)l * 1048576;  // f16 ELEMENT stride (32^4)
    const float* Wr = convs_w + (size_t)l * 1048576;
    const float* bs = convs_b + 32 * l;
    if (pre) {
      if (l == 0)
        gemm5<4, 16, false, true, false><<<256, 512, 0, stream>>>(Wl, Wr, cur, bs, nxt);
      else
        gemm5<4, 16, true, true, false><<<256, 512, 0, stream>>>(Wl, Wr, cur, bs, nxt);
    } else {
      if (l == 0)
        gemm5<4, 16, false, false, false><<<256, 512, 0, stream>>>(Wl, Wr, cur, bs, nxt);
      else
        gemm5<4, 16, true, false, false><<<256, 512, 0, stream>>>(Wl, Wr, cur, bs, nxt);
    }
  }

  // l=19 wrote bufA
  out_conv5<<<64, 256, 0, stream>>>(bufA, out_w, out_b, out);
}

// Round 6
// 1494.873 us; speedup vs baseline: 1.0276x; 1.0276x over previous
//
#include <hip/hip_runtime.h>

// GoL CNN v7: v6 with the cross-block K-reduction done via plain-stored
// per-slice partial buffers summed in the NEXT kernel's staging (no atomics,
// no memsets). Plans by ws_size: A f32x8sl(75.6MB) / B f16x8sl(58.8MB) /
// C f16x2sl(48.3MB, proven floor).

typedef _Float16 f16;
typedef _Float16 f16x8 __attribute__((ext_vector_type(8)));
typedef float f32x4 __attribute__((ext_vector_type(4)));
typedef float f32x16 __attribute__((ext_vector_type(16)));

__device__ __forceinline__ int mwrap(int j) {
  int t = j - 31;
  if ((unsigned)t <= 31u) return t;  // middle
  return (j & 1) ? 0 : 31;           // borders alternate
}

#define BROW 104        // f16 per Bsh row (208 B, 16B-aligned)
#define PELEM 524288    // elements per partial buffer [16][32][32][32]

// KCH: input channels per slice. T: oy rows per wave. SUMP: partials to sum
// when staging input (0 = read raw f32 x). INCONV: 1-channel k-split layer.
template <int KCH, int T, int SUMP, typename PTI, typename PTO, bool RELUIN, bool INCONV>
__global__ __launch_bounds__(512, 2) void gemm7(
    const f16* __restrict__ Wf,     // frag-major f16 weights (layer base)
    const PTI* __restrict__ src,    // x (SUMP==0) or partial base (SUMP bufs)
    const float* __restrict__ bias, // [32]
    PTO* __restrict__ dstP) {       // partial base; block writes slot sli
  constexpr int SLICES = INCONV ? 4 : (32 / KCH);
  constexpr int OYS = 32 / (8 * T);
  constexpr int CHUNKS = INCONV ? 8 : KCH * 32;
  constexpr int KYPP = INCONV ? 8 : (KCH >= 16 ? 8 : 16);
  constexpr int NPH = CHUNKS / KYPP;
  constexpr int ABYTES = KYPP * 2048;
  constexpr int UPT = KYPP / 4;
  constexpr int NCH = INCONV ? 1 : KCH;

  __shared__ __align__(16) char smem[2 * ABYTES + NCH * 32 * BROW * 2 + 16];
  f16* Bsh = (f16*)(smem + 2 * ABYTES);

  const int tid = threadIdx.x;
  const int lane = tid & 63;
  const int w = tid >> 6;
  const int ox = lane & 31;
  const int sl = lane >> 5;
  const int q = (OYS == 1) ? 0 : (blockIdx.x % OYS);
  const int sli = (blockIdx.x / OYS) % SLICES;
  const int b = blockIdx.x / (OYS * SLICES);
  const int c0 = INCONV ? 0 : sli * KCH;
  const int ky0 = INCONV ? 8 * sli : 0;
  const int oy0 = q * (8 * T) + w * T;

  const f16* Wsl = Wf + ((size_t)(c0 * 32 + ky0) << 10);

  // --- stage B rows once: sum partials (or read x), relu?, f16 ---
  {
    constexpr int NB = NCH * 384;
    for (int base = 0; base < NB; base += 512) {
      const int id = base + tid;
      if (id < NB) {
        const int cl = id / 384, rem = id % 384;
        const int y = rem / 12, u9 = rem % 12;
        f16x8 v;
#pragma unroll
        for (int i = 0; i < 8; ++i) {
          const int x = mwrap(u9 * 8 + i);
          float t;
          if constexpr (SUMP == 0) {
            t = (float)src[(b * 32 + y) * 32 + x];
          } else {
            t = 0.f;
            const size_t eidx = (((size_t)b * 32 + c0 + cl) * 32 + y) * 32 + x;
#pragma unroll
            for (int sp = 0; sp < SUMP; ++sp)
              t += (float)src[(size_t)sp * PELEM + eidx];
          }
          if (RELUIN) t = fmaxf(t, 0.f);
          v[i] = (f16)t;
        }
        *(f16x8*)(Bsh + (cl * 32 + y) * BROW + u9 * 8) = v;
      }
    }
  }

  int4 pf[UPT];
  auto prefA = [&](int ph1) {
    const char* gp = (const char*)Wsl + (size_t)ph1 * ABYTES;
#pragma unroll
    for (int u = 0; u < UPT; ++u)
      pf[u] = *(const int4*)(gp + (u * 512 + tid) * 16);
  };
  auto wrA = [&](int nb) {
    char* lp = smem + nb * ABYTES;
#pragma unroll
    for (int u = 0; u < UPT; ++u)
      *(int4*)(lp + (u * 512 + tid) * 16) = pf[u];
  };

  prefA(0);
  wrA(0);
  __syncthreads();

  f32x16 acc[T][2] = {};
  f16x8 Bw[2][T][2];  // [parity][t][kxh] rolling window
  const int Rbase = ox + 4 * sl;

  auto loadB = [&](int cloc, int j, int kxh) -> f16x8 {
    const int y = mwrap(j);
    const int* R = (const int*)Bsh + (cloc * 32 + y) * (BROW / 2) + Rbase + 8 * kxh;
    int4 t;
    t.x = R[0]; t.y = R[1]; t.z = R[2]; t.w = R[3];
    return __builtin_bit_cast(f16x8, t);
  };

  for (int ph = 0; ph < NPH; ++ph) {
    if (ph + 1 < NPH) prefA(ph + 1);
    const char* Ab = smem + (ph & 1) * ABYTES;
#pragma unroll
    for (int kk = 0; kk < KYPP; ++kk) {
      const int g = ph * KYPP + kk;
      const int cloc = g >> 5;
      const int ky = ky0 + (g & 31);
      const int p = g & 1;
      const int J0 = 2 * oy0 + ky;
      if ((g & 31) < 2) {
#pragma unroll
        for (int t = 0; t < T; ++t) {
          Bw[p][t][0] = loadB(cloc, J0 + 2 * t, 0);
          Bw[p][t][1] = loadB(cloc, J0 + 2 * t, 1);
        }
      } else {
#pragma unroll
        for (int t = 0; t + 1 < T; ++t) {
          Bw[p][t][0] = Bw[p][t + 1][0];
          Bw[p][t][1] = Bw[p][t + 1][1];
        }
        Bw[p][T - 1][0] = loadB(cloc, J0 + 2 * (T - 1), 0);
        Bw[p][T - 1][1] = loadB(cloc, J0 + 2 * (T - 1), 1);
      }
#pragma unroll
      for (int kxh = 0; kxh < 2; ++kxh) {
        f16x8 a = *(const f16x8*)(Ab + (kk * 2 + kxh) * 1024 + lane * 16);
#pragma unroll
        for (int t = 0; t < T; ++t)
          acc[t][kxh] =
              __builtin_amdgcn_mfma_f32_32x32x16_f16(a, Bw[p][t][kxh], acc[t][kxh], 0, 0, 0);
      }
    }
    if (ph + 1 < NPH) wrA((ph + 1) & 1);
    __syncthreads();
  }

  // --- epilogue: plain stores of the K-partial (bias on slice 0 only) ---
  PTO* dst = dstP + (size_t)sli * PELEM;
#pragma unroll
  for (int t = 0; t < T; ++t) {
    const int oy = oy0 + t;
#pragma unroll
    for (int r = 0; r < 16; ++r) {
      const int co = (r & 3) + 8 * (r >> 2) + 4 * sl;  // m74/m101 C-layout
      float v = acc[t][0][r] + acc[t][1][r];
      if (sli == 0) v += bias[co];
      dst[(((size_t)b * 32 + co) * 32 + oy) * 32 + ox] = (PTO)v;
    }
  }
}

// frag-major f16 weights (layout validated v3-v6)
__global__ void convert_w3(const float* __restrict__ in_w,
                           const float* __restrict__ convs_w,
                           f16* __restrict__ WfIn, f16* __restrict__ WfH) {
  const int total = 4096 + 20 * 131072;
  for (int g = blockIdx.x * blockDim.x + threadIdx.x; g < total;
       g += gridDim.x * blockDim.x) {
    const float* src;
    f16* dst;
    int chunk, lanE, c, ky, kxh;
    if (g < 4096) {
      chunk = g >> 6; lanE = g & 63;
      kxh = chunk & 1; ky = chunk >> 1; c = 0;
      const int co = lanE & 31, ss = lanE >> 5;
      src = in_w + ((size_t)co * 32 + ky) * 32 + kxh * 16 + ss * 8;
      dst = WfIn + (size_t)chunk * 512 + lanE * 8;
    } else {
      const int h = g - 4096;
      const int layer = h >> 17, r = h & 131071;
      chunk = r >> 6; lanE = r & 63;
      kxh = chunk & 1;
      const int t = chunk >> 1;
      ky = t & 31; c = t >> 5;
      const int co = lanE & 31, ss = lanE >> 5;
      src = convs_w + (size_t)layer * 1048576 +
            ((size_t)(co * 32 + c) * 32 + ky) * 32 + kxh * 16 + ss * 8;
      dst = WfH + (size_t)layer * 1048576 + (size_t)chunk * 512 + lanE * 8;
    }
    f32x4 u0 = *(const f32x4*)src;
    f32x4 u1 = *(const f32x4*)(src + 4);
    f16x8 v;
    v[0] = (f16)u0[0]; v[1] = (f16)u0[1]; v[2] = (f16)u0[2]; v[3] = (f16)u0[3];
    v[4] = (f16)u1[0]; v[5] = (f16)u1[1]; v[6] = (f16)u1[2]; v[7] = (f16)u1[3];
    *(f16x8*)dst = v;
  }
}

template <int SUMP, typename PT>
__global__ void out_conv7(const PT* __restrict__ P, const float* __restrict__ ow,
                          const float* __restrict__ ob, float* __restrict__ out) {
  const int o = blockIdx.x * 256 + threadIdx.x;  // 16384
  const int b = o >> 10, rem = o & 1023;
  float s = ob[0];
#pragma unroll
  for (int c = 0; c < 32; ++c) {
    float h = 0.f;
#pragma unroll
    for (int sp = 0; sp < SUMP; ++sp)
      h += (float)P[(size_t)sp * PELEM + ((size_t)(b * 32 + c) << 10) + rem];
    s += ow[c] * fmaxf(h, 0.f);
  }
  out[o] = s;
}

extern "C" void kernel_launch(void* const* d_in, const int* in_sizes, int n_in,
                              void* d_out, int out_size, void* d_ws,
                              size_t ws_size, hipStream_t stream) {
  const float* x = (const float*)d_in[0];
  const float* in_w = (const float*)d_in[1];
  const float* in_b = (const float*)d_in[2];
  const float* convs_w = (const float*)d_in[3];
  const float* convs_b = (const float*)d_in[4];
  const float* out_w = (const float*)d_in[5];
  const float* out_b = (const float*)d_in[6];
  float* out = (float*)d_out;

  char* ws = (char*)d_ws;
  f16* WfIn = (f16*)ws;                 // 64 KB
  f16* WfH = (f16*)(ws + 65536);        // 41,943,040 B
  char* sides = ws + 65536 + 41943040ull;

  convert_w3<<<2048, 256, 0, stream>>>(in_w, convs_w, WfIn, WfH);

  const size_t needA = 42008576ull + 2 * 8 * (size_t)PELEM * 4;  // 75,563,008
  const size_t needB = 42008576ull + 2 * 8 * (size_t)PELEM * 2;  // 58,785,792
  // C: sideE holds 4 partials (in_conv), sideO holds 2:  48,300,032

  if (ws_size >= needA) {
    float* E = (float*)sides;
    float* O = E + 8 * (size_t)PELEM;
    gemm7<1, 4, 0, float, float, false, true><<<64, 512, 0, stream>>>(WfIn, x, in_b, E);
    for (int l = 0; l < 20; ++l) {
      float* cur = (l & 1) ? O : E;
      float* nxt = (l & 1) ? E : O;
      const f16* Wl = WfH + (size_t)l * 1048576;
      const float* bs = convs_b + 32 * l;
      if (l == 0)
        gemm7<4, 2, 4, float, float, false, false><<<256, 512, 0, stream>>>(Wl, cur, bs, nxt);
      else
        gemm7<4, 2, 8, float, float, true, false><<<256, 512, 0, stream>>>(Wl, cur, bs, nxt);
    }
    out_conv7<8, float><<<64, 256, 0, stream>>>(E, out_w, out_b, out);  // l19 wrote E
  } else if (ws_size >= needB) {
    f16* E = (f16*)sides;
    f16* O = E + 8 * (size_t)PELEM;
    gemm7<1, 4, 0, float, f16, false, true><<<64, 512, 0, stream>>>(WfIn, x, in_b, E);
    for (int l = 0; l < 20; ++l) {
      f16* cur = (l & 1) ? O : E;
      f16* nxt = (l & 1) ? E : O;
      const f16* Wl = WfH + (size_t)l * 1048576;
      const float* bs = convs_b + 32 * l;
      if (l == 0)
        gemm7<4, 2, 4, f16, f16, false, false><<<256, 512, 0, stream>>>(Wl, cur, bs, nxt);
      else
        gemm7<4, 2, 8, f16, f16, true, false><<<256, 512, 0, stream>>>(Wl, cur, bs, nxt);
    }
    out_conv7<8, f16><<<64, 256, 0, stream>>>(E, out_w, out_b, out);
  } else {
    // plan C: 2 slices (KCH=16), T=1 (OYS=4), grid 128; fits 48.3 MB
    f16* E = (f16*)sides;
    f16* O = E + 4 * (size_t)PELEM;
    gemm7<1, 4, 0, float, f16, false, true><<<64, 512, 0, stream>>>(WfIn, x, in_b, E);
    for (int l = 0; l < 20; ++l) {
      f16* cur = (l & 1) ? O : E;
      f16* nxt = (l & 1) ? E : O;
      const f16* Wl = WfH + (size_t)l * 1048576;
      const float* bs = convs_b + 32 * l;
      if (l == 0)
        gemm7<16, 1, 4, f16, f16, false, false><<<128, 512, 0, stream>>>(Wl, cur, bs, nxt);
      else
        gemm7<16, 1, 2, f16, f16, true, false><<<128, 512, 0, stream>>>(Wl, cur, bs, nxt);
    }
    out_conv7<2, f16><<<64, 256, 0, stream>>>(E, out_w, out_b, out);
  }
}